// Round 11
// baseline (3452.373 us; speedup 1.0000x reference)
//
#include <hip/hip_runtime.h>
#include <cmath>

#define HID 64
#define IN_C 128
#define RW 64   // fixed row width (max degree 16+6sigma ~ 45 << 64)

__device__ __forceinline__ float rl(float v, int k) {
    return __uint_as_float(__builtin_amdgcn_readlane(__float_as_uint(v), k));
}
__device__ __forceinline__ float bflo(unsigned u) { return __uint_as_float(u << 16); }
__device__ __forceinline__ float bfhi(unsigned u) { return __uint_as_float(u & 0xffff0000u); }
__device__ __forceinline__ unsigned bfpack(float lo, float hi) {
    unsigned a = __float_as_uint(lo), b = __float_as_uint(hi);
    a = (a + 0x7fffu + ((a >> 16) & 1u)) >> 16;
    b = (b + 0x7fffu + ((b >> 16) & 1u)) & 0xffff0000u;
    return a | b;
}

// ---- VALU cross-lane helpers --------------------------------------------
__device__ __forceinline__ float xadd8(float x) {
    int t = __builtin_amdgcn_update_dpp(0, __float_as_int(x), 0x128, 0xF, 0xF, true);
    return x + __int_as_float(t);
}
#if __has_builtin(__builtin_amdgcn_permlane16_swap)
typedef unsigned uvec2 __attribute__((ext_vector_type(2)));
__device__ __forceinline__ float xadd16(float x) {
    uvec2 r = __builtin_amdgcn_permlane16_swap(__float_as_uint(x), __float_as_uint(x), false, false);
    return __uint_as_float(r[0]) + __uint_as_float(r[1]);
}
#else
__device__ __forceinline__ float xadd16(float x) { return x + __shfl_xor(x, 16); }
#endif
#if __has_builtin(__builtin_amdgcn_permlane32_swap)
typedef unsigned uvec2b __attribute__((ext_vector_type(2)));
__device__ __forceinline__ float xadd32(float x) {
    uvec2b r = __builtin_amdgcn_permlane32_swap(__float_as_uint(x), __float_as_uint(x), false, false);
    return __uint_as_float(r[0]) + __uint_as_float(r[1]);
}
#else
__device__ __forceinline__ float xadd32(float x) { return x + __shfl_xor(x, 32); }
#endif
__device__ __forceinline__ float pairswap(float x) {
    int t = __builtin_amdgcn_update_dpp(0, __float_as_int(x), 0xB1, 0xF, 0xF, true);
    return __int_as_float(t);
}

// ---- CSR build: memset(cnt) + one fused scatter into fixed[N][RW] -------

__global__ void k_scat(const int* __restrict__ src, const int* __restrict__ dst,
                       int* __restrict__ cnt, int* __restrict__ fixed, int E) {
    int e = blockIdx.x * blockDim.x + threadIdx.x;
    if (e < E) {
        int d = dst[e];
        int p = atomicAdd(&cnt[d], 1);
        if (p < RW) fixed[(size_t)d * RW + p] = src[e];
    }
}

// ---- input projection: h0(bf16) = relu(x @ lin0_w^T) --------------------
__global__ __launch_bounds__(256) void k_lin0(const float* __restrict__ x,
                                              const float* __restrict__ w,
                                              const float* __restrict__ b,
                                              unsigned* __restrict__ h0, int N) {
    __shared__ float Wt[IN_C * 65];
    for (int i = threadIdx.x; i < IN_C * HID; i += 256) {
        int o = i >> 7, k = i & 127;
        Wt[k * 65 + o] = w[i];
    }
    __syncthreads();
    int lane = threadIdx.x & 63;
    int wid = (blockIdx.x * blockDim.x + threadIdx.x) >> 6;
    int nw = (gridDim.x * blockDim.x) >> 6;
    float bias = b[lane];
    for (int n0 = wid; n0 < N; n0 += 2 * nw) {
        int n1 = n0 + nw;
        bool v1 = n1 < N;
        int n1c = v1 ? n1 : n0;
        float xa0 = x[(size_t)n0 * IN_C + lane];
        float xa1 = x[(size_t)n0 * IN_C + 64 + lane];
        float xb0 = x[(size_t)n1c * IN_C + lane];
        float xb1 = x[(size_t)n1c * IN_C + 64 + lane];
        float acc0 = bias, acc1 = bias;
#pragma unroll
        for (int k = 0; k < 64; ++k) {
            float wv = Wt[k * 65 + lane];
            acc0 = fmaf(rl(xa0, k), wv, acc0);
            acc1 = fmaf(rl(xb0, k), wv, acc1);
        }
#pragma unroll
        for (int k = 0; k < 64; ++k) {
            float wv = Wt[(64 + k) * 65 + lane];
            acc0 = fmaf(rl(xa1, k), wv, acc0);
            acc1 = fmaf(rl(xb1, k), wv, acc1);
        }
        acc0 = fmaxf(acc0, 0.f);
        acc1 = fmaxf(acc1, 0.f);
        float p0 = pairswap(acc0);
        float p1 = pairswap(acc1);
        if ((lane & 1) == 0) {
            h0[(size_t)n0 * 32 + (lane >> 1)] = bfpack(acc0, p0);
            if (v1) h0[(size_t)n1 * 32 + (lane >> 1)] = bfpack(acc1, p1);
        }
    }
}

// ---- fused GCN2 layer: single-node, minimal VGPR, 8 waves/SIMD ----------
// __launch_bounds__(256, 8): cap at 64 VGPR -> occupancy 32 waves/CU (2x
// every prior variant). Fixed-width rows kill the row_ptr round-trip.
__device__ __forceinline__ void acc8(float* a, const uint4& q) {
    a[0] += bflo(q.x); a[1] += bfhi(q.x);
    a[2] += bflo(q.y); a[3] += bfhi(q.y);
    a[4] += bflo(q.z); a[5] += bfhi(q.z);
    a[6] += bflo(q.w); a[7] += bfhi(q.w);
}
__device__ __forceinline__ void mask4(uint4& q, bool v) {
    q.x = v ? q.x : 0u; q.y = v ? q.y : 0u; q.z = v ? q.z : 0u; q.w = v ? q.w : 0u;
}

__global__ __launch_bounds__(256, 8) void k_layer(const uint4* __restrict__ hin,
                                                  const uint4* __restrict__ h0,
                                                  unsigned* __restrict__ hout,
                                                  const float* __restrict__ W,
                                                  const int* __restrict__ cnt,
                                                  const int* __restrict__ fixed,
                                                  float beta, int N) {
    __shared__ uint4 Wp[8 * 64];   // bf16x8 of W'[8k8+0..7][c], W'=(1-b)I+bW
    for (int idx = threadIdx.x; idx < 8 * 64; idx += 256) {
        int k8 = idx >> 6, c = idx & 63;
        float wv[8];
#pragma unroll
        for (int m = 0; m < 8; ++m) {
            int k = 8 * k8 + m;
            float v = beta * W[k * 64 + c];
            if (k == c) v += 1.f - beta;
            wv[m] = v;
        }
        uint4 p;
        p.x = bfpack(wv[0], wv[1]); p.y = bfpack(wv[2], wv[3]);
        p.z = bfpack(wv[4], wv[5]); p.w = bfpack(wv[6], wv[7]);
        Wp[idx] = p;
    }
    __syncthreads();

    int lane = threadIdx.x & 63;
    int sub = lane >> 3;   // edge slot 0..7
    int cg = lane & 7;     // channel quad 0..7
    int wid = (blockIdx.x * blockDim.x + threadIdx.x) >> 6;
    int nw = (gridDim.x * blockDim.x) >> 6;

    for (int n = wid; n < N; n += nw) {
        int d = min(cnt[n], RW);
        const int* row = fixed + (size_t)n * RW;
        float a[8];
#pragma unroll
        for (int c = 0; c < 8; ++c) a[c] = 0.f;
        int j = 0;
        for (; j + 16 <= d; j += 16) {      // full 16-edge rounds, 2 KB in flight
            int i0 = row[j + sub];
            int i1 = row[j + 8 + sub];
            uint4 q0 = hin[(size_t)i0 * 8 + cg];
            uint4 q1 = hin[(size_t)i1 * 8 + cg];
            acc8(a, q0);
            acc8(a, q1);
        }
        if (j < d) {                        // tail, clamped + masked
            int last = d - 1;
            int i0 = row[min(j + sub, last)];
            int i1 = row[min(j + 8 + sub, last)];
            uint4 q0 = hin[(size_t)i0 * 8 + cg];
            uint4 q1 = hin[(size_t)i1 * 8 + cg];
            mask4(q0, j + sub < d);
            mask4(q1, j + 8 + sub < d);
            acc8(a, q0);
            acc8(a, q1);
        }
        // reduce over 8 edge slots — VALU DPP/permlane
#pragma unroll
        for (int c = 0; c < 8; ++c) a[c] = xadd8(a[c]);
#pragma unroll
        for (int c = 0; c < 8; ++c) a[c] = xadd16(a[c]);
#pragma unroll
        for (int c = 0; c < 8; ++c) a[c] = xadd32(a[c]);

        // residual z = 0.9*agg + 0.1*h0 (channel 8*cg+c in reg c)
        uint4 hq = h0[(size_t)n * 8 + cg];
        a[0] = 0.9f * a[0] + 0.1f * bflo(hq.x);
        a[1] = 0.9f * a[1] + 0.1f * bfhi(hq.x);
        a[2] = 0.9f * a[2] + 0.1f * bflo(hq.y);
        a[3] = 0.9f * a[3] + 0.1f * bfhi(hq.y);
        a[4] = 0.9f * a[4] + 0.1f * bflo(hq.z);
        a[5] = 0.9f * a[5] + 0.1f * bfhi(hq.z);
        a[6] = 0.9f * a[6] + 0.1f * bflo(hq.w);
        a[7] = 0.9f * a[7] + 0.1f * bfhi(hq.w);

        // r_c = sum_k z_k W'[k][c], c = lane; z_{8k8+m} = rl(a[m], k8)
        float g0 = 0.f, g1 = 0.f, g2 = 0.f, g3 = 0.f;
#pragma unroll
        for (int k8 = 0; k8 < 8; ++k8) {
            uint4 wp = Wp[k8 * 64 + lane];
            g0 = fmaf(rl(a[0], k8), bflo(wp.x), g0);
            g1 = fmaf(rl(a[1], k8), bfhi(wp.x), g1);
            g2 = fmaf(rl(a[2], k8), bflo(wp.y), g2);
            g3 = fmaf(rl(a[3], k8), bfhi(wp.y), g3);
            g0 = fmaf(rl(a[4], k8), bflo(wp.z), g0);
            g1 = fmaf(rl(a[5], k8), bfhi(wp.z), g1);
            g2 = fmaf(rl(a[6], k8), bflo(wp.w), g2);
            g3 = fmaf(rl(a[7], k8), bfhi(wp.w), g3);
        }
        float r = fmaxf((g0 + g1) + (g2 + g3), 0.f);
        float rn = pairswap(r);
        if ((lane & 1) == 0) hout[(size_t)n * 32 + (lane >> 1)] = bfpack(r, rn);
    }
}

// ---- output projection: out = h @ lin1_w^T + b --------------------------
__global__ __launch_bounds__(256) void k_lin1(const unsigned* __restrict__ h,
                                              const float* __restrict__ w,
                                              const float* __restrict__ b,
                                              float* __restrict__ out, int N) {
    __shared__ float Wt[HID * 65];
    for (int i = threadIdx.x; i < HID * HID; i += 256) {
        int o = i >> 6, k = i & 63;
        Wt[k * 65 + o] = w[i];
    }
    __syncthreads();
    int lane = threadIdx.x & 63;
    int wid = (blockIdx.x * blockDim.x + threadIdx.x) >> 6;
    int nw = (gridDim.x * blockDim.x) >> 6;
    float bias = b[lane];
    for (int n0 = wid; n0 < N; n0 += 2 * nw) {
        int n1 = n0 + nw;
        bool v1 = n1 < N;
        int n1c = v1 ? n1 : n0;
        unsigned ua = h[(size_t)n0 * 32 + (lane >> 1)];
        unsigned ub = h[(size_t)n1c * 32 + (lane >> 1)];
        float ha = (lane & 1) ? bfhi(ua) : bflo(ua);
        float hb = (lane & 1) ? bfhi(ub) : bflo(ub);
        float acc0 = bias, acc1 = bias;
#pragma unroll
        for (int k = 0; k < 64; ++k) {
            float wv = Wt[k * 65 + lane];
            acc0 = fmaf(rl(ha, k), wv, acc0);
            acc1 = fmaf(rl(hb, k), wv, acc1);
        }
        out[(size_t)n0 * HID + lane] = acc0;
        if (v1) out[(size_t)n1 * HID + lane] = acc1;
    }
}

extern "C" void kernel_launch(void* const* d_in, const int* in_sizes, int n_in,
                              void* d_out, int out_size, void* d_ws, size_t ws_size,
                              hipStream_t stream) {
    const float* x      = (const float*)d_in[0];
    const int*   ei     = (const int*)d_in[1];
    const float* lin0_w = (const float*)d_in[2];
    const float* lin0_b = (const float*)d_in[3];
    const float* lin1_w = (const float*)d_in[4];
    const float* lin1_b = (const float*)d_in[5];
    const float* conv_w = (const float*)d_in[6];

    int N = in_sizes[0] / IN_C;
    int E = in_sizes[1] / 2;
    const int* src = ei;
    const int* dst = ei + E;

    // bf16 state buffers: N*32 uints each; cnt N; fixed N*RW
    unsigned* h0 = (unsigned*)d_ws;
    unsigned* hA = h0 + (size_t)N * 32;
    unsigned* hB = hA + (size_t)N * 32;
    int* cnt   = (int*)(hB + (size_t)N * 32);
    int* fixed = cnt + N;

    // CSR build: memset + fused scatter (no hist/scan passes)
    hipMemsetAsync(cnt, 0, (size_t)N * sizeof(int), stream);
    k_scat<<<(E + 255) / 256, 256, 0, stream>>>(src, dst, cnt, fixed, E);

    // input projection -> h0 (bf16)
    k_lin0<<<1024, 256, 0, stream>>>(x, lin0_w, lin0_b, h0, N);

    // 16 fused layers
    const unsigned* cur = h0;
    for (int l = 0; l < 16; ++l) {
        float beta = (float)log(0.5 / (double)(l + 1) + 1.0);
        unsigned* nxt = (l & 1) ? hB : hA;
        k_layer<<<2048, 256, 0, stream>>>((const uint4*)cur, (const uint4*)h0, nxt,
                                          conv_w + (size_t)l * HID * HID,
                                          cnt, fixed, beta, N);
        cur = nxt;
    }

    // output projection
    k_lin1<<<1024, 256, 0, stream>>>(cur, lin1_w, lin1_b, (float*)d_out, N);
}

// Round 12
// 2026.759 us; speedup vs baseline: 1.7034x; 1.7034x over previous
//
#include <hip/hip_runtime.h>
#include <cmath>

#define HID 64
#define IN_C 128

__device__ __forceinline__ float rl(float v, int k) {
    return __uint_as_float(__builtin_amdgcn_readlane(__float_as_uint(v), k));
}
__device__ __forceinline__ float bflo(unsigned u) { return __uint_as_float(u << 16); }
__device__ __forceinline__ float bfhi(unsigned u) { return __uint_as_float(u & 0xffff0000u); }
__device__ __forceinline__ unsigned bfpack(float lo, float hi) {
    unsigned a = __float_as_uint(lo), b = __float_as_uint(hi);
    a = (a + 0x7fffu + ((a >> 16) & 1u)) >> 16;
    b = (b + 0x7fffu + ((b >> 16) & 1u)) & 0xffff0000u;
    return a | b;
}

// DPP add helpers. CTRL: 0xB1 xor1, 0x4E xor2, 0x124 ror4, 0x128 ror8
template <int CTRL>
__device__ __forceinline__ float dppadd(float x) {
    int t = __builtin_amdgcn_update_dpp(0, __float_as_int(x), CTRL, 0xF, 0xF, true);
    return x + __int_as_float(t);
}
__device__ __forceinline__ float pairswap(float x) {
    int t = __builtin_amdgcn_update_dpp(0, __float_as_int(x), 0xB1, 0xF, 0xF, true);
    return __int_as_float(t);
}
__device__ __forceinline__ void mask4(uint4& q, bool v) {
    q.x = v ? q.x : 0u; q.y = v ? q.y : 0u; q.z = v ? q.z : 0u; q.w = v ? q.w : 0u;
}
__device__ __forceinline__ void acc8(float* a, const uint4& q) {
    a[0] += bflo(q.x); a[1] += bfhi(q.x);
    a[2] += bflo(q.y); a[3] += bfhi(q.y);
    a[4] += bflo(q.z); a[5] += bfhi(q.z);
    a[6] += bflo(q.w); a[7] += bfhi(q.w);
}

// ---- CSR build ----------------------------------------------------------

__global__ void k_hist(const int* __restrict__ dst, int* __restrict__ counts, int E) {
    int e = blockIdx.x * blockDim.x + threadIdx.x;
    if (e < E) atomicAdd(&counts[dst[e]], 1);
}

__global__ void k_scan_block(const int* __restrict__ counts, int* __restrict__ row_ptr,
                             int* __restrict__ chunk_sums, int n) {
    __shared__ int s[1024];
    int i = blockIdx.x * 1024 + threadIdx.x;
    int v = (i < n) ? counts[i] : 0;
    s[threadIdx.x] = v;
    __syncthreads();
    for (int off = 1; off < 1024; off <<= 1) {
        int t = (threadIdx.x >= off) ? s[threadIdx.x - off] : 0;
        __syncthreads();
        s[threadIdx.x] += t;
        __syncthreads();
    }
    if (i < n) row_ptr[i] = s[threadIdx.x] - v;   // exclusive
    if (threadIdx.x == 1023) chunk_sums[blockIdx.x] = s[1023];
}

__global__ void k_scan_fix(int* __restrict__ row_ptr, const int* __restrict__ chunk_sums,
                           int n, int total) {
    __shared__ int base_s;
    if (threadIdx.x == 0) {
        int b = 0;
        for (int c = 0; c < (int)blockIdx.x; ++c) b += chunk_sums[c];
        base_s = b;
    }
    __syncthreads();
    int i = blockIdx.x * 1024 + threadIdx.x;
    if (i < n) row_ptr[i] += base_s;
    if (i == 0) row_ptr[n] = total;
}

__global__ void k_fill(const int* __restrict__ src, const int* __restrict__ dst,
                       const int* __restrict__ row_ptr, int* __restrict__ cursor,
                       int* __restrict__ col_idx, int E) {
    int e = blockIdx.x * blockDim.x + threadIdx.x;
    if (e < E) {
        int d = dst[e];
        int pos = row_ptr[d] + atomicAdd(&cursor[d], 1);
        col_idx[pos] = src[e];
    }
}

// ---- input projection -> h0 slabs (R9-verified) --------------------------
// Slab layout: S[cg][n] = 16B slice (channels 8cg..8cg+7, bf16 pair-packed).
__global__ __launch_bounds__(256) void k_lin0(const float* __restrict__ x,
                                              const float* __restrict__ w,
                                              const float* __restrict__ b,
                                              unsigned* __restrict__ S, int N) {
    __shared__ float Wt[IN_C * 65];
    for (int i = threadIdx.x; i < IN_C * HID; i += 256) {
        int o = i >> 7, k = i & 127;
        Wt[k * 65 + o] = w[i];
    }
    __syncthreads();
    size_t N4 = (size_t)N * 4;
    int lane = threadIdx.x & 63;
    int wid = (blockIdx.x * blockDim.x + threadIdx.x) >> 6;
    int nw = (gridDim.x * blockDim.x) >> 6;
    float bias = b[lane];
    size_t waddr = (size_t)(lane >> 3) * N4 + ((lane >> 1) & 3);
    for (int n0 = wid; n0 < N; n0 += 2 * nw) {
        int n1 = n0 + nw;
        bool v1 = n1 < N;
        int n1c = v1 ? n1 : n0;
        float xa0 = x[(size_t)n0 * IN_C + lane];
        float xa1 = x[(size_t)n0 * IN_C + 64 + lane];
        float xb0 = x[(size_t)n1c * IN_C + lane];
        float xb1 = x[(size_t)n1c * IN_C + 64 + lane];
        float acc0 = bias, acc1 = bias;
#pragma unroll
        for (int k = 0; k < 64; ++k) {
            float wv = Wt[k * 65 + lane];
            acc0 = fmaf(rl(xa0, k), wv, acc0);
            acc1 = fmaf(rl(xb0, k), wv, acc1);
        }
#pragma unroll
        for (int k = 0; k < 64; ++k) {
            float wv = Wt[(64 + k) * 65 + lane];
            acc0 = fmaf(rl(xa1, k), wv, acc0);
            acc1 = fmaf(rl(xb1, k), wv, acc1);
        }
        acc0 = fmaxf(acc0, 0.f);
        acc1 = fmaxf(acc1, 0.f);
        float p0 = pairswap(acc0);
        float p1 = pairswap(acc1);
        if ((lane & 1) == 0) {
            S[waddr + (size_t)n0 * 4] = bfpack(acc0, p0);
            if (v1) S[waddr + (size_t)n1 * 4] = bfpack(acc1, p1);
        }
    }
}

// ---- phase A: slab gather + residual -> z (bf16 rows) --------------------
// cg = blockIdx&7: XCD round-robin keeps slab cg (1.6MB) in that XCD's L2.
// Correctness never depends on the mapping; only locality does.
// lane = (ns = lane>>4 node slot 0..3, es = lane&15 edge slot).
// Two 4-node groups per iteration (dual chains, 2KB in flight).
__global__ __launch_bounds__(256, 8) void k_aggr(const unsigned* __restrict__ Sin,
                                                 const unsigned* __restrict__ h0S,
                                                 unsigned* __restrict__ zrow,
                                                 const int* __restrict__ row_ptr,
                                                 const int* __restrict__ col_idx,
                                                 int N) {
    int lane = threadIdx.x & 63;
    int ns = lane >> 4, es = lane & 15;
    int cg = blockIdx.x & 7;
    int grp = blockIdx.x >> 3;
    int ngrp = gridDim.x >> 3;
    int wv = threadIdx.x >> 6;
    const uint4* slab = (const uint4*)(Sin + (size_t)cg * N * 4);
    const uint4* h0sl = (const uint4*)(h0S + (size_t)cg * N * 4);
    uint4* zr = (uint4*)zrow;

    int gw = grp * 4 + wv;        // wave id within slab
    int nwv = ngrp * 4;           // waves per slab

    for (int nb = gw * 8; nb < N; nb += nwv * 8) {
        int nA = nb + ns, nB = nb + 4 + ns;
        bool vA = nA < N, vB = nB < N;
        int nAc = vA ? nA : N - 1;
        int nBc = vB ? nB : N - 1;
        int bA = row_ptr[nAc], eA = row_ptr[nAc + 1];
        int bB = row_ptr[nBc], eB = row_ptr[nBc + 1];
        int dA = vA ? eA - bA : 0, dB = vB ? eB - bB : 0;
        int baseA = (dA > 0) ? bA : 0, lastA = (dA > 0) ? eA - 1 : 0;
        int baseB = (dB > 0) ? bB : 0, lastB = (dB > 0) ? eB - 1 : 0;
        // wave-uniform round count
        int dm = max(dA, dB);
        dm = max(dm, __shfl_xor(dm, 16));
        dm = max(dm, __shfl_xor(dm, 32));

        float aA[8], aB[8];
#pragma unroll
        for (int c = 0; c < 8; ++c) { aA[c] = 0.f; aB[c] = 0.f; }
        for (int j = 0; j < dm; j += 16) {
            int iA = col_idx[min(baseA + j + es, lastA)];
            int iB = col_idx[min(baseB + j + es, lastB)];
            uint4 qA = slab[iA];
            uint4 qB = slab[iB];
            mask4(qA, j + es < dA);
            mask4(qB, j + es < dB);
            acc8(aA, qA);
            acc8(aB, qB);
        }
        // reduce over 16 edge slots (VALU DPP): xor1, xor2, ror4, ror8
#pragma unroll
        for (int c = 0; c < 8; ++c) { aA[c] = dppadd<0xB1>(aA[c]);  aB[c] = dppadd<0xB1>(aB[c]); }
#pragma unroll
        for (int c = 0; c < 8; ++c) { aA[c] = dppadd<0x4E>(aA[c]);  aB[c] = dppadd<0x4E>(aB[c]); }
#pragma unroll
        for (int c = 0; c < 8; ++c) { aA[c] = dppadd<0x124>(aA[c]); aB[c] = dppadd<0x124>(aB[c]); }
#pragma unroll
        for (int c = 0; c < 8; ++c) { aA[c] = dppadd<0x128>(aA[c]); aB[c] = dppadd<0x128>(aB[c]); }

        uint4 hA = h0sl[nAc];
        uint4 hB = h0sl[nBc];
        float zA[8], zB[8];
        zA[0] = 0.9f * aA[0] + 0.1f * bflo(hA.x);
        zA[1] = 0.9f * aA[1] + 0.1f * bfhi(hA.x);
        zA[2] = 0.9f * aA[2] + 0.1f * bflo(hA.y);
        zA[3] = 0.9f * aA[3] + 0.1f * bfhi(hA.y);
        zA[4] = 0.9f * aA[4] + 0.1f * bflo(hA.z);
        zA[5] = 0.9f * aA[5] + 0.1f * bfhi(hA.z);
        zA[6] = 0.9f * aA[6] + 0.1f * bflo(hA.w);
        zA[7] = 0.9f * aA[7] + 0.1f * bfhi(hA.w);
        zB[0] = 0.9f * aB[0] + 0.1f * bflo(hB.x);
        zB[1] = 0.9f * aB[1] + 0.1f * bfhi(hB.x);
        zB[2] = 0.9f * aB[2] + 0.1f * bflo(hB.y);
        zB[3] = 0.9f * aB[3] + 0.1f * bfhi(hB.y);
        zB[4] = 0.9f * aB[4] + 0.1f * bflo(hB.z);
        zB[5] = 0.9f * aB[5] + 0.1f * bfhi(hB.z);
        zB[6] = 0.9f * aB[6] + 0.1f * bflo(hB.w);
        zB[7] = 0.9f * aB[7] + 0.1f * bfhi(hB.w);
        uint4 zqA, zqB;
        zqA.x = bfpack(zA[0], zA[1]); zqA.y = bfpack(zA[2], zA[3]);
        zqA.z = bfpack(zA[4], zA[5]); zqA.w = bfpack(zA[6], zA[7]);
        zqB.x = bfpack(zB[0], zB[1]); zqB.y = bfpack(zB[2], zB[3]);
        zqB.z = bfpack(zB[4], zB[5]); zqB.w = bfpack(zB[6], zB[7]);
        if (es == 0) {
            if (vA) zr[(size_t)nA * 8 + cg] = zqA;
            if (vB) zr[(size_t)nB * 8 + cg] = zqB;
        }
    }
}

// ---- phase B: dense r = relu(z @ W'), W' = (1-b)I + bW (R9-verified) -----
__global__ __launch_bounds__(256) void k_gemm(const uint4* __restrict__ zrow,
                                              unsigned* __restrict__ Sout,
                                              const float* __restrict__ W,
                                              float beta, int N) {
    __shared__ uint4 Wp[8 * 64];   // bf16x8 of W'[8k8+0..7][c]
    for (int idx = threadIdx.x; idx < 8 * 64; idx += 256) {
        int k8 = idx >> 6, c = idx & 63;
        float wv[8];
#pragma unroll
        for (int m = 0; m < 8; ++m) {
            int k = 8 * k8 + m;
            float v = beta * W[k * 64 + c];
            if (k == c) v += 1.f - beta;
            wv[m] = v;
        }
        uint4 p;
        p.x = bfpack(wv[0], wv[1]); p.y = bfpack(wv[2], wv[3]);
        p.z = bfpack(wv[4], wv[5]); p.w = bfpack(wv[6], wv[7]);
        Wp[idx] = p;
    }
    __syncthreads();

    size_t N4 = (size_t)N * 4;
    int lane = threadIdx.x & 63;
    int cg = lane & 7;
    int wid = (blockIdx.x * blockDim.x + threadIdx.x) >> 6;
    int nw = (gridDim.x * blockDim.x) >> 6;
    size_t waddr = (size_t)(lane >> 3) * N4 + ((lane >> 1) & 3);

    for (int n0 = 2 * wid; n0 < N; n0 += 2 * nw) {
        int n1 = n0 + 1;
        bool v1 = n1 < N;
        int n1c = v1 ? n1 : n0;
        uint4 zqA = zrow[(size_t)n0 * 8 + cg];
        uint4 zqB = zrow[(size_t)n1c * 8 + cg];
        float zA[8], zB[8];
        zA[0] = bflo(zqA.x); zA[1] = bfhi(zqA.x);
        zA[2] = bflo(zqA.y); zA[3] = bfhi(zqA.y);
        zA[4] = bflo(zqA.z); zA[5] = bfhi(zqA.z);
        zA[6] = bflo(zqA.w); zA[7] = bfhi(zqA.w);
        zB[0] = bflo(zqB.x); zB[1] = bfhi(zqB.x);
        zB[2] = bflo(zqB.y); zB[3] = bfhi(zqB.y);
        zB[4] = bflo(zqB.z); zB[5] = bfhi(zqB.z);
        zB[6] = bflo(zqB.w); zB[7] = bfhi(zqB.w);

        float gA0 = 0.f, gA1 = 0.f, gA2 = 0.f, gA3 = 0.f;
        float gB0 = 0.f, gB1 = 0.f, gB2 = 0.f, gB3 = 0.f;
#pragma unroll
        for (int k8 = 0; k8 < 8; ++k8) {
            uint4 wp = Wp[k8 * 64 + lane];
            gA0 = fmaf(rl(zA[0], k8), bflo(wp.x), gA0);
            gA1 = fmaf(rl(zA[1], k8), bfhi(wp.x), gA1);
            gA2 = fmaf(rl(zA[2], k8), bflo(wp.y), gA2);
            gA3 = fmaf(rl(zA[3], k8), bfhi(wp.y), gA3);
            gA0 = fmaf(rl(zA[4], k8), bflo(wp.z), gA0);
            gA1 = fmaf(rl(zA[5], k8), bfhi(wp.z), gA1);
            gA2 = fmaf(rl(zA[6], k8), bflo(wp.w), gA2);
            gA3 = fmaf(rl(zA[7], k8), bfhi(wp.w), gA3);
            gB0 = fmaf(rl(zB[0], k8), bflo(wp.x), gB0);
            gB1 = fmaf(rl(zB[1], k8), bfhi(wp.x), gB1);
            gB2 = fmaf(rl(zB[2], k8), bflo(wp.y), gB2);
            gB3 = fmaf(rl(zB[3], k8), bfhi(wp.y), gB3);
            gB0 = fmaf(rl(zB[4], k8), bflo(wp.z), gB0);
            gB1 = fmaf(rl(zB[5], k8), bfhi(wp.z), gB1);
            gB2 = fmaf(rl(zB[6], k8), bflo(wp.w), gB2);
            gB3 = fmaf(rl(zB[7], k8), bfhi(wp.w), gB3);
        }
        float rA = fmaxf((gA0 + gA1) + (gA2 + gA3), 0.f);
        float rB = fmaxf((gB0 + gB1) + (gB2 + gB3), 0.f);
        float rAn = pairswap(rA);
        float rBn = pairswap(rB);
        if ((lane & 1) == 0) {
            Sout[waddr + (size_t)n0 * 4] = bfpack(rA, rAn);
            if (v1) Sout[waddr + (size_t)n1 * 4] = bfpack(rB, rBn);
        }
    }
}

// ---- output projection (slab input, R9-verified) -------------------------
__global__ __launch_bounds__(256) void k_lin1(const unsigned* __restrict__ S,
                                              const float* __restrict__ w,
                                              const float* __restrict__ b,
                                              float* __restrict__ out, int N) {
    __shared__ float Wt[HID * 65];
    for (int i = threadIdx.x; i < HID * HID; i += 256) {
        int o = i >> 6, k = i & 63;
        Wt[k * 65 + o] = w[i];
    }
    __syncthreads();
    size_t N4 = (size_t)N * 4;
    int lane = threadIdx.x & 63;
    int wid = (blockIdx.x * blockDim.x + threadIdx.x) >> 6;
    int nw = (gridDim.x * blockDim.x) >> 6;
    float bias = b[lane];
    size_t raddr = (size_t)(lane >> 3) * N4 + ((lane >> 1) & 3);
    for (int n0 = wid; n0 < N; n0 += 2 * nw) {
        int n1 = n0 + nw;
        bool v1 = n1 < N;
        int n1c = v1 ? n1 : n0;
        unsigned ua = S[raddr + (size_t)n0 * 4];
        unsigned ub = S[raddr + (size_t)n1c * 4];
        float ha = (lane & 1) ? bfhi(ua) : bflo(ua);
        float hb = (lane & 1) ? bfhi(ub) : bflo(ub);
        float acc0 = bias, acc1 = bias;
#pragma unroll
        for (int k = 0; k < 64; ++k) {
            float wv = Wt[k * 65 + lane];
            acc0 = fmaf(rl(ha, k), wv, acc0);
            acc1 = fmaf(rl(hb, k), wv, acc1);
        }
        out[(size_t)n0 * HID + lane] = acc0;
        if (v1) out[(size_t)n1 * HID + lane] = acc1;
    }
}

extern "C" void kernel_launch(void* const* d_in, const int* in_sizes, int n_in,
                              void* d_out, int out_size, void* d_ws, size_t ws_size,
                              hipStream_t stream) {
    const float* x      = (const float*)d_in[0];
    const int*   ei     = (const int*)d_in[1];
    const float* lin0_w = (const float*)d_in[2];
    const float* lin0_b = (const float*)d_in[3];
    const float* lin1_w = (const float*)d_in[4];
    const float* lin1_b = (const float*)d_in[5];
    const float* conv_w = (const float*)d_in[6];

    int N = in_sizes[0] / IN_C;
    int E = in_sizes[1] / 2;
    const int* src = ei;
    const int* dst = ei + E;

    // slab state buffers: 8 slabs x N x 4 uints = N*32 uints each
    unsigned* h0S = (unsigned*)d_ws;
    unsigned* SA  = h0S + (size_t)N * 32;
    unsigned* SB  = SA + (size_t)N * 32;
    int* row_ptr    = (int*)(SB + (size_t)N * 32);
    int* cursor     = row_ptr + (N + 1);
    int* col_idx    = cursor + N;
    int* chunk_sums = col_idx + E;
    // z buffer lives in d_out (dead until k_lin1 fully rewrites d_out)
    unsigned* Z = (unsigned*)d_out;

    int nch = (N + 1023) / 1024;

    // CSR build
    hipMemsetAsync(cursor, 0, (size_t)N * sizeof(int), stream);
    k_hist<<<(E + 255) / 256, 256, 0, stream>>>(dst, cursor, E);
    k_scan_block<<<nch, 1024, 0, stream>>>(cursor, row_ptr, chunk_sums, N);
    k_scan_fix<<<nch, 1024, 0, stream>>>(row_ptr, chunk_sums, N, E);
    hipMemsetAsync(cursor, 0, (size_t)N * sizeof(int), stream);
    k_fill<<<(E + 255) / 256, 256, 0, stream>>>(src, dst, row_ptr, cursor, col_idx, E);

    // input projection -> h0 slabs
    k_lin0<<<1024, 256, 0, stream>>>(x, lin0_w, lin0_b, h0S, N);

    // 16 layers: slab-gather (z) then dense GEMM (next slab state)
    const unsigned* cur = h0S;
    for (int l = 0; l < 16; ++l) {
        float beta = (float)log(0.5 / (double)(l + 1) + 1.0);
        unsigned* nxt = (l & 1) ? SB : SA;
        k_aggr<<<2048, 256, 0, stream>>>(cur, h0S, Z, row_ptr, col_idx, N);
        k_gemm<<<2048, 256, 0, stream>>>((const uint4*)Z, nxt,
                                         conv_w + (size_t)l * HID * HID, beta, N);
        cur = nxt;
    }

    // output projection (reads final slab state, overwrites d_out)
    k_lin1<<<1024, 256, 0, stream>>>(cur, lin1_w, lin1_b, (float*)d_out, N);
}